// Round 1
// baseline (90.522 us; speedup 1.0000x reference)
//
#include <hip/hip_runtime.h>

// GMP (generalized memory polynomial), B=32, T=4096, M=11, DEG=5 (K=4 powers).
//
// out[b,t] = sum_{m=0..10} xc[b,t+m-10] *
//              ( W0[m] + sum_{k=1..4} sum_{l=0..10} |xc[b,t+l+m-20]|^k * W1[k-1,l,m] )
// with xc zero-padded for negative time indices.
// W0[m] = Weight[m]; W1[k,l,m] = Weight[11 + k*121 + l*11 + m].

#define GMP_M 11
#define GMP_K 4
#define GMP_T 4096
#define GMP_B 32
#define TILE 256
#define HALO 20   // 2*(M-1)

__global__ __launch_bounds__(TILE) void gmp_kernel(const float* __restrict__ x,
                                                   const float* __restrict__ W,
                                                   float* __restrict__ out) {
    const int b  = blockIdx.y;
    const int t0 = blockIdx.x * TILE;
    const int lt = threadIdx.x;

    __shared__ float2 xs[TILE + HALO];  // xs[i] = xc[b, t0 - 20 + i]
    __shared__ float4 ps[TILE + HALO];  // (a, a^2, a^3, a^4) at same position

    const float2* xb = (const float2*)(x + (size_t)b * GMP_T * 2);

    for (int i = lt; i < TILE + HALO; i += TILE) {
        int g = t0 - HALO + i;                 // global time index, may be negative
        float2 v = make_float2(0.f, 0.f);
        if (g >= 0) v = xb[g];                 // g <= t0+255 <= T-1 always
        xs[i] = v;
        float r2 = v.x * v.x + v.y * v.y;
        float a  = sqrtf(r2);
        ps[i] = make_float4(a, r2, r2 * a, r2 * r2);
    }
    __syncthreads();

    // Pull the 21-wide power window into registers.
    float4 P[HALO + 1];
#pragma unroll
    for (int q = 0; q <= HALO; ++q) P[q] = ps[lt + q];

    float2 acc = make_float2(0.f, 0.f);
#pragma unroll
    for (int m = 0; m < GMP_M; ++m) {
        float gm = W[m];                       // W0[m] (uniform -> s_load)
#pragma unroll
        for (int l = 0; l < GMP_M; ++l) {
            float4 p = P[l + m];
            gm += p.x * W[GMP_M + 0 * 121 + l * 11 + m]
                + p.y * W[GMP_M + 1 * 121 + l * 11 + m]
                + p.z * W[GMP_M + 2 * 121 + l * 11 + m]
                + p.w * W[GMP_M + 3 * 121 + l * 11 + m];
        }
        float2 xv = xs[lt + m + (GMP_M - 1)];  // xc[b, t+m-10]
        acc.x += xv.x * gm;
        acc.y += xv.y * gm;
    }

    float2* ob = (float2*)(out + ((size_t)b * GMP_T + t0) * 2);
    ob[lt] = acc;
}

extern "C" void kernel_launch(void* const* d_in, const int* in_sizes, int n_in,
                              void* d_out, int out_size, void* d_ws, size_t ws_size,
                              hipStream_t stream) {
    (void)in_sizes; (void)n_in; (void)d_ws; (void)ws_size; (void)out_size;
    const float* x = (const float*)d_in[0];
    // d_in[1] is h_0 (unused by the reference computation)
    const float* W = (const float*)d_in[2];
    float* out = (float*)d_out;

    dim3 grid(GMP_T / TILE, GMP_B, 1);   // 16 x 32 = 512 blocks
    dim3 block(TILE, 1, 1);
    gmp_kernel<<<grid, block, 0, stream>>>(x, W, out);
}

// Round 2
// 72.152 us; speedup vs baseline: 1.2546x; 1.2546x over previous
//
#include <hip/hip_runtime.h>

// GMP (generalized memory polynomial), B=32, T=4096, M=11, DEG=5 (K=4 powers).
//
// out[b,t] = sum_{m=0..10} xc[b,t+m-10] *
//              ( W0[m] + sum_{k=1..4} sum_{l=0..10} |xc[b,t+l+m-20]|^k * W1[k-1,l,m] )
// with xc zero-padded for negative time indices.
// W0[m] = Weight[m]; W1[k,l,m] = Weight[11 + k*121 + l*11 + m].
//
// Split: half A of the block (threads 0..127, waves 0-1) handles k=1,2
// (powers a, a^2) plus the W0 term; half B (threads 128..255, waves 2-3)
// handles k=3,4 (a^3, a^4). Partials combined through LDS.
// This doubles wave-parallelism (4096 waves = 4/SIMD) and halves the
// per-thread FMA chain + SGPR weight pressure vs the round-1 kernel.

#define GMP_M 11
#define GMP_T 4096
#define GMP_B 32
#define TILE 128
#define HALO 20   // 2*(M-1)

__global__ __launch_bounds__(256) void gmp_kernel(const float* __restrict__ x,
                                                  const float* __restrict__ W,
                                                  float* __restrict__ out) {
    const int b   = blockIdx.y;
    const int t0  = blockIdx.x * TILE;
    const int tid = threadIdx.x;
    const int lt  = tid & (TILE - 1);
    // wave-uniform half index (waves 0-1 -> 0, waves 2-3 -> 1); readfirstlane
    // forces it into an SGPR so the weight base stays on the s_load path.
    const int half = __builtin_amdgcn_readfirstlane(tid >> 7);

    __shared__ float2 xs[TILE + HALO];   // xc[b, t0-20+i]
    __shared__ float2 pA[TILE + HALO];   // (a,    a^2 )
    __shared__ float2 pB[TILE + HALO];   // (a^3,  a^4 )
    __shared__ float2 psum[TILE];        // half-B partials

    const float2* xb = (const float2*)(x + (size_t)b * GMP_T * 2);

    for (int i = tid; i < TILE + HALO; i += 256) {
        int g = t0 - HALO + i;
        float2 v = make_float2(0.f, 0.f);
        if (g >= 0) v = xb[g];           // g <= t0+127 <= T-1 always
        xs[i] = v;
        float r2 = v.x * v.x + v.y * v.y;
        float a  = sqrtf(r2);
        pA[i] = make_float2(a, r2);
        pB[i] = make_float2(r2 * a, r2 * r2);
    }
    __syncthreads();

    // This half's two power channels, 21-wide window, in registers.
    const float2* __restrict__ pS = half ? pB : pA;
    float2 P[HALO + 1];
#pragma unroll
    for (int q = 0; q <= HALO; ++q) P[q] = pS[lt + q];

    // Weight base for this half: k-pair {0,1} or {2,3} of W1[k,l,m].
    const float* __restrict__ Wb = W + GMP_M + half * 2 * 121;

    float2 acc = make_float2(0.f, 0.f);
#pragma unroll
    for (int m = 0; m < GMP_M; ++m) {
        float gm = half ? 0.f : W[m];    // W0 term only on half A (uniform)
#pragma unroll
        for (int l = 0; l < GMP_M; ++l) {
            float2 p = P[l + m];
            gm += p.x * Wb[0 * 121 + l * 11 + m]
                + p.y * Wb[1 * 121 + l * 11 + m];
        }
        float2 xv = xs[lt + m + (GMP_M - 1)];   // xc[b, t+m-10]
        acc.x += xv.x * gm;
        acc.y += xv.y * gm;
    }

    if (half) {                          // wave-uniform branch
        psum[lt] = acc;
    }
    __syncthreads();
    if (!half) {
        float2 o = psum[lt];
        o.x += acc.x;
        o.y += acc.y;
        float2* ob = (float2*)(out + ((size_t)b * GMP_T + t0) * 2);
        ob[lt] = o;
    }
}

extern "C" void kernel_launch(void* const* d_in, const int* in_sizes, int n_in,
                              void* d_out, int out_size, void* d_ws, size_t ws_size,
                              hipStream_t stream) {
    (void)in_sizes; (void)n_in; (void)d_ws; (void)ws_size; (void)out_size;
    const float* x = (const float*)d_in[0];
    // d_in[1] is h_0 (unused by the reference computation)
    const float* W = (const float*)d_in[2];
    float* out = (float*)d_out;

    dim3 grid(GMP_T / TILE, GMP_B, 1);   // 32 x 32 = 1024 blocks
    dim3 block(256, 1, 1);
    gmp_kernel<<<grid, block, 0, stream>>>(x, W, out);
}

// Round 3
// 63.306 us; speedup vs baseline: 1.4299x; 1.1397x over previous
//
#include <hip/hip_runtime.h>

// GMP (generalized memory polynomial), B=32, T=4096, M=11, DEG=5 (K=4 powers).
//
// out[b,t] = sum_{m=0..10} xc[b,t+m-10] *
//              ( W0[m] + sum_{k=1..4} sum_{l=0..10} |xc[b,t+l+m-20]|^k * W1[k-1,l,m] )
// with xc zero-padded for negative time indices.
// W0[m] = Weight[m]; W1[k,l,m] = Weight[11 + k*121 + l*11 + m].
//
// 4-way k-split: wave q of each 256-thread block handles power channel q+1
// (a, a^2, a^3, a^4); wave 0 also adds the W0 tap term. Partials combined
// through LDS. Per-wave weight set = 121 floats (near-fits SGPR file, kills
// the s_load reload churn of earlier rounds); ~50 VGPR/thread -> 8 waves/SIMD
// (full occupancy: 2048 blocks x 4 waves = 32 waves/CU).

#define GMP_M 11
#define GMP_T 4096
#define GMP_B 32
#define TILE 64
#define HALO 20   // 2*(M-1)

__global__ __launch_bounds__(256) void gmp_kernel(const float* __restrict__ x,
                                                  const float* __restrict__ W,
                                                  float* __restrict__ out) {
    const int b   = blockIdx.y;
    const int t0  = blockIdx.x * TILE;
    const int tid = threadIdx.x;
    const int lt  = tid & 63;
    // wave-uniform power-channel index (wave q handles |x|^(q+1))
    const int q   = __builtin_amdgcn_readfirstlane(tid >> 6);

    __shared__ float2 xs[TILE + HALO];      // xc[b, t0-20+i]
    __shared__ float  pk[4][TILE + HALO];   // SoA power channels: a, a^2, a^3, a^4
    __shared__ float2 psum[3 * TILE];       // partials from waves 1..3

    const float2* xb = (const float2*)(x + (size_t)b * GMP_T * 2);

    for (int i = tid; i < TILE + HALO; i += 256) {
        int g = t0 - HALO + i;
        float2 v = make_float2(0.f, 0.f);
        if (g >= 0) v = xb[g];              // g <= t0+63 <= T-1 always
        xs[i] = v;
        float r2 = v.x * v.x + v.y * v.y;
        float a  = sqrtf(r2);
        pk[0][i] = a;
        pk[1][i] = r2;
        pk[2][i] = r2 * a;
        pk[3][i] = r2 * r2;
    }
    __syncthreads();

    // This wave's power channel, 21-wide window, in registers (21 VGPRs).
    float P[HALO + 1];
#pragma unroll
    for (int s = 0; s <= HALO; ++s) P[s] = pk[q][lt + s];

    // Weight slab for this wave's k: W1[q, l, m], 121 floats, wave-uniform.
    const float* __restrict__ Wb = W + GMP_M + q * 121;

    float2 acc = make_float2(0.f, 0.f);
#pragma unroll
    for (int m = 0; m < GMP_M; ++m) {
        float gm = (q == 0) ? W[m] : 0.f;   // W0 tap term only on wave 0
#pragma unroll
        for (int l = 0; l < GMP_M; ++l)
            gm += P[l + m] * Wb[l * 11 + m];
        float2 xv = xs[lt + m + (GMP_M - 1)];   // xc[b, t+m-10]
        acc.x += xv.x * gm;
        acc.y += xv.y * gm;
    }

    if (q) {                                // wave-uniform branch
        psum[(q - 1) * TILE + lt] = acc;
    }
    __syncthreads();
    if (q == 0) {
        float2 o = acc;
#pragma unroll
        for (int j = 0; j < 3; ++j) {
            float2 p = psum[j * TILE + lt];
            o.x += p.x;
            o.y += p.y;
        }
        float2* ob = (float2*)(out + ((size_t)b * GMP_T + t0) * 2);
        ob[lt] = o;
    }
}

extern "C" void kernel_launch(void* const* d_in, const int* in_sizes, int n_in,
                              void* d_out, int out_size, void* d_ws, size_t ws_size,
                              hipStream_t stream) {
    (void)in_sizes; (void)n_in; (void)d_ws; (void)ws_size; (void)out_size;
    const float* x = (const float*)d_in[0];
    // d_in[1] is h_0 (unused by the reference computation)
    const float* W = (const float*)d_in[2];
    float* out = (float*)d_out;

    dim3 grid(GMP_T / TILE, GMP_B, 1);   // 64 x 32 = 2048 blocks
    dim3 block(256, 1, 1);
    gmp_kernel<<<grid, block, 0, stream>>>(x, W, out);
}